// Round 15
// baseline (983.053 us; speedup 1.0000x reference)
//
#include <hip/hip_runtime.h>
#include <stdint.h>

// ============================================================================
// LESSON (rounds 0-14): `if (off > ws_size) return;` silently launched NOTHING
// for 15 rounds (ws demand 269.8MB > ws_size). Zeros pass outputs 0,3,4,5 under
// the harness's GLOBAL absmax threshold (13.52), so the bail was invisible and
// mimicked a memory-visibility bug. Never bail silently; always fit ws_size.
// ============================================================================

#define B_SZ 4096
#define O_SZ 512
#define A_SZ 64
#define H_SZ 2048
#define Z_SZ 256

typedef __attribute__((ext_vector_type(4))) float f32x4;
typedef __attribute__((ext_vector_type(8))) short s16x8;

__device__ __forceinline__ uint16_t f2b(float f) {
  union { float f; uint32_t u; } v; v.f = f;
  uint32_t u = v.u;
  uint32_t r = (u + 0x7FFFu + ((u >> 16) & 1u)) >> 16;
  return (uint16_t)r;
}
__device__ __forceinline__ float b2f(uint16_t h) {
  union { uint32_t u; float f; } v; v.u = ((uint32_t)h) << 16; return v.f;
}
__device__ __forceinline__ float clip10(float v) { return fminf(fmaxf(v, -10.0f), 10.0f); }

// ---------------- fp32 [R,C] -> bf16 strided [R, dstLd] ----------------
__global__ void convert_kernel(const float* __restrict__ src, uint16_t* __restrict__ dst,
                               int C8, int C, int dstLd, int ngroups) {
  int i = blockIdx.x * 256 + threadIdx.x;
  if (i >= ngroups) return;
  int row = i / C8;
  int cg = i - row * C8;
  const f32x4* s = (const f32x4*)(src + (size_t)row * C + (size_t)cg * 8);
  f32x4 lo = s[0], hi = s[1];
  s16x8 p;
  p[0] = (short)f2b(lo[0]); p[1] = (short)f2b(lo[1]);
  p[2] = (short)f2b(lo[2]); p[3] = (short)f2b(lo[3]);
  p[4] = (short)f2b(hi[0]); p[5] = (short)f2b(hi[1]);
  p[6] = (short)f2b(hi[2]); p[7] = (short)f2b(hi[3]);
  *(s16x8*)(dst + (size_t)row * dstLd + (size_t)cg * 8) = p;
}

// ---------------- async global->LDS, 16B per lane ----------------
__device__ __forceinline__ void gload_lds16(const uint16_t* g, uint16_t* l) {
  __builtin_amdgcn_global_load_lds(
      (const __attribute__((address_space(1))) uint32_t*)g,
      (__attribute__((address_space(3))) uint32_t*)(uintptr_t)(void*)l,
      16, 0, 0);
}

// ---------------- MFMA bf16 GEMM: C[M,N] = A[M,K](lda) @ W[N,K]^T + bias --------
// EPI: 0 = fp32 out, 1 = bf16 out + relu, 2 = bf16 out
template <int EPI>
__global__ __launch_bounds__(256)
void gemm_bt(const uint16_t* __restrict__ A, int lda,
             const uint16_t* __restrict__ W,
             const float* __restrict__ bias,
             void* __restrict__ Cout, int ldc,
             int Nt, int K) {
  __shared__ uint16_t As[128 * 64];
  __shared__ uint16_t Ws[128 * 64];
  int mtile = blockIdx.x / Nt;
  int ntile = blockIdx.x - mtile * Nt;
  const int row0 = mtile << 7, col0 = ntile << 7;
  const int t = threadIdx.x;
  const int w = t >> 6, l = t & 63;
  const int wr = w >> 1, wc = w & 1;
  const int sr = l >> 3, scg = l & 7;
  const int fr = l & 15, fq = l >> 4;

  f32x4 acc[4][4] = {};

  const uint16_t* Abase = A + (size_t)(row0 + w * 32 + sr) * lda + scg * 8;
  const uint16_t* Wbase = W + (size_t)(col0 + w * 32 + sr) * K + scg * 8;

  for (int k0 = 0; k0 < K; k0 += 64) {
#pragma unroll
    for (int j = 0; j < 4; ++j)
      gload_lds16(Abase + (size_t)(j * 8) * lda + k0, &As[(w * 32 + j * 8) * 64]);
#pragma unroll
    for (int j = 0; j < 4; ++j)
      gload_lds16(Wbase + (size_t)(j * 8) * K + k0, &Ws[(w * 32 + j * 8) * 64]);
    __syncthreads();
#pragma unroll
    for (int ks = 0; ks < 2; ++ks) {
      s16x8 fa[4], fb[4];
#pragma unroll
      for (int m = 0; m < 4; ++m)
        fa[m] = *(const s16x8*)&As[(wr * 64 + m * 16 + fr) * 64 + ks * 32 + fq * 8];
#pragma unroll
      for (int n = 0; n < 4; ++n)
        fb[n] = *(const s16x8*)&Ws[(wc * 64 + n * 16 + fr) * 64 + ks * 32 + fq * 8];
#pragma unroll
      for (int m = 0; m < 4; ++m)
#pragma unroll
        for (int n = 0; n < 4; ++n)
          acc[m][n] = __builtin_amdgcn_mfma_f32_16x16x32_bf16(fa[m], fb[n], acc[m][n], 0, 0, 0);
    }
    __syncthreads();
  }

#pragma unroll
  for (int m = 0; m < 4; ++m) {
    int grow = row0 + wr * 64 + m * 16 + fq * 4;
#pragma unroll
    for (int n = 0; n < 4; ++n) {
      int gcol = col0 + wc * 64 + n * 16 + fr;
      float bs = bias[gcol];
#pragma unroll
      for (int i = 0; i < 4; ++i) {
        float v = acc[m][n][i] + bs;
        if (EPI == 1) v = fmaxf(v, 0.0f);
        if (EPI == 0)
          ((float*)Cout)[(size_t)(grow + i) * ldc + gcol] = v;
        else
          ((uint16_t*)Cout)[(size_t)(grow + i) * ldc + gcol] = f2b(v);
      }
    }
  }
}

// ---------------- tier1 reparameterization (bf16 stats in) ----------------
__global__ void z_kernel_t1(const uint16_t* __restrict__ es, const float* __restrict__ eps,
                            float* __restrict__ oz, float* __restrict__ omu,
                            float* __restrict__ olq,
                            uint16_t* __restrict__ zh, uint16_t* __restrict__ rnn) {
  int i = blockIdx.x * 256 + threadIdx.x;  // B*Z
  int b = i >> 8, j = i & 255;
  float mu = b2f(es[(size_t)b * 512 + j]);
  float lq = clip10(b2f(es[(size_t)b * 512 + 256 + j]));
  float z = mu + eps[i] * __expf(0.5f * lq);
  oz[i] = z; omu[i] = mu; olq[i] = lq;
  zh[(size_t)b * 2304 + j] = f2b(z);
  rnn[(size_t)b * 832 + 512 + j] = f2b(z);
}

// ---------------- block reduction (256 threads, reusable) ----------------
__device__ __forceinline__ float block_sum256(float v) {
  __shared__ float ps[4];
#pragma unroll
  for (int o = 32; o > 0; o >>= 1) v += __shfl_xor(v, o, 64);
  int l = threadIdx.x & 63, w = threadIdx.x >> 6;
  if (l == 0) ps[w] = v;
  __syncthreads();
  float r = ps[0] + ps[1] + ps[2] + ps[3];
  __syncthreads();
  return r;
}

// ---------------- tier1 epilogue: GRU + nll + kl (bf16 gi/gh/dec/stats) ---------
__global__ __launch_bounds__(256)
void gru_fused_t1(const uint16_t* __restrict__ gi_s, const uint16_t* __restrict__ gh_s,
                  const float* __restrict__ hp, const float* __restrict__ x,
                  const uint16_t* __restrict__ dec, const uint16_t* __restrict__ pst,
                  const uint16_t* __restrict__ es,
                  float* __restrict__ out_h, float* __restrict__ out_nll,
                  float* __restrict__ out_kl, int row0) {
  int bl = blockIdx.x, t = threadIdx.x;
  int gb = row0 + bl;
  size_t gbase = (size_t)bl * 6144 + (size_t)t * 8;
  s16x8 ir = *(const s16x8*)(gi_s + gbase);
  s16x8 iz = *(const s16x8*)(gi_s + gbase + 2048);
  s16x8 inn = *(const s16x8*)(gi_s + gbase + 4096);
  s16x8 hr = *(const s16x8*)(gh_s + gbase);
  s16x8 hz = *(const s16x8*)(gh_s + gbase + 2048);
  s16x8 hn = *(const s16x8*)(gh_s + gbase + 4096);
  size_t hbase = (size_t)gb * 2048 + (size_t)t * 8;
  f32x4 h0 = *(const f32x4*)(hp + hbase);
  f32x4 h1v = *(const f32x4*)(hp + hbase + 4);
  f32x4 o0, o1;
#pragma unroll
  for (int e = 0; e < 8; ++e) {
    float r = 1.f / (1.f + __expf(-(b2f((uint16_t)ir[e]) + b2f((uint16_t)hr[e]))));
    float zg = 1.f / (1.f + __expf(-(b2f((uint16_t)iz[e]) + b2f((uint16_t)hz[e]))));
    float nv = b2f((uint16_t)inn[e]) + r * b2f((uint16_t)hn[e]);
    float t2 = __expf(-2.f * fabsf(nv));
    float n = (1.f - t2) / (1.f + t2);
    n = (nv >= 0.f) ? n : -n;
    float hv = (e < 4) ? h0[e] : h1v[e - 4];
    float o = (1.f - zg) * n + zg * hv;
    if (e < 4) o0[e] = o; else o1[e - 4] = o;
  }
  *(f32x4*)(out_h + hbase) = o0;
  *(f32x4*)(out_h + hbase + 4) = o1;

  // NLL over 512 cols
  float s = 0.f;
#pragma unroll
  for (int rr = 0; rr < 2; ++rr) {
    int j = t + rr * 256;
    float mu = b2f(dec[(size_t)gb * 1024 + j]);
    float lx = clip10(b2f(dec[(size_t)gb * 1024 + 512 + j]));
    float d = x[(size_t)gb * 512 + j] - mu;
    s += d * d * __expf(-lx) + lx;
  }
  s = block_sum256(s);
  if (t == 0) out_nll[gb] = 0.5f * s;

  // KL over 256 cols
  float mu_p = b2f(pst[(size_t)gb * 512 + t]);
  float lp = b2f(pst[(size_t)gb * 512 + 256 + t]);
  float mu_q = b2f(es[(size_t)gb * 512 + t]);
  float lq = clip10(b2f(es[(size_t)gb * 512 + 256 + t]));
  float dq = mu_q - mu_p;
  float enl = __expf(-lp);
  float kv = dq * dq * enl + __expf(lq) * enl + (lp - lq) - 1.0f;
  kv = block_sum256(kv);
  if (t == 0) out_kl[gb] = 0.5f * kv;
}

// ================= tier 2: naive fp32 sliced pipeline =================
// 3-region concat GEMM, fp32 in/out, one thread per C element.
template <int MODE>  // 0 plain, 1 relu
__global__ __launch_bounds__(256)
void gemm_nv(const float* __restrict__ A0, int ld0, int s1,
             const float* __restrict__ A1, int ld1, int s2,
             const float* __restrict__ A2, int ld2,
             const float* __restrict__ W, const float* __restrict__ bias,
             float* __restrict__ C, int N, int K) {
  int nb = N >> 8;
  int m = blockIdx.x / nb;
  int n = (blockIdx.x - m * nb) * 256 + threadIdx.x;
  const float* w = W + (size_t)n * K;
  float acc = 0.f;
  int k = 0;
  for (; k < s1; ++k) acc += A0[(size_t)m * ld0 + k] * w[k];
  for (; k < s2; ++k) acc += A1[(size_t)m * ld1 + (k - s1)] * w[k];
  for (; k < K; ++k) acc += A2[(size_t)m * ld2 + (k - s2)] * w[k];
  acc += bias[n];
  if (MODE == 1) acc = fmaxf(acc, 0.f);
  C[(size_t)m * N + n] = acc;
}

__global__ void z_nv(const float* __restrict__ ests, const float* __restrict__ eps,
                     float* __restrict__ oz, float* __restrict__ omu,
                     float* __restrict__ olq, float* __restrict__ zs, int row0, int nR) {
  int i = blockIdx.x * 256 + threadIdx.x;  // R*Z
  if (i >= nR * 256) return;
  int bl = i >> 8, j = i & 255;
  size_t g = (size_t)(row0 + bl) * 256 + j;
  float mu = ests[(size_t)bl * 512 + j];
  float lq = clip10(ests[(size_t)bl * 512 + 256 + j]);
  float z = mu + eps[g] * __expf(0.5f * lq);
  oz[g] = z; omu[g] = mu; olq[g] = lq;
  zs[(size_t)bl * 256 + j] = z;
}

__global__ void nll_nv(const float* __restrict__ x, const float* __restrict__ decs,
                       float* __restrict__ out, int row0) {
  int bl = blockIdx.x, l = threadIdx.x;  // 64 threads
  int gb = row0 + bl;
  float s = 0.f;
  for (int j = l; j < 512; j += 64) {
    float mu = decs[(size_t)bl * 1024 + j];
    float lx = clip10(decs[(size_t)bl * 1024 + 512 + j]);
    float d = x[(size_t)gb * 512 + j] - mu;
    s += d * d * __expf(-lx) + lx;
  }
#pragma unroll
  for (int o = 32; o > 0; o >>= 1) s += __shfl_xor(s, o, 64);
  if (l == 0) out[gb] = 0.5f * s;
}

__global__ void kl_nv(const float* __restrict__ psts, const float* __restrict__ ests,
                      float* __restrict__ out, int row0) {
  int bl = blockIdx.x, l = threadIdx.x;  // 64 threads
  int gb = row0 + bl;
  float s = 0.f;
  for (int j = l; j < 256; j += 64) {
    float mu_p = psts[(size_t)bl * 512 + j];
    float lp = psts[(size_t)bl * 512 + 256 + j];
    float mu_q = ests[(size_t)bl * 512 + j];
    float lq = clip10(ests[(size_t)bl * 512 + 256 + j]);
    float d = mu_q - mu_p;
    float enl = __expf(-lp);
    s += d * d * enl + __expf(lq) * enl + (lp - lq) - 1.0f;
  }
#pragma unroll
  for (int o = 32; o > 0; o >>= 1) s += __shfl_xor(s, o, 64);
  if (l == 0) out[gb] = 0.5f * s;
}

__global__ void gru_nv(const float* __restrict__ gis, const float* __restrict__ ghs,
                       const float* __restrict__ hp, float* __restrict__ ho,
                       int row0, int nR) {
  int i = blockIdx.x * 256 + threadIdx.x;  // R*2048
  if (i >= nR * 2048) return;
  int bl = i >> 11, j = i & 2047;
  size_t lb = (size_t)bl * 6144 + j;
  float r = 1.f / (1.f + __expf(-(gis[lb] + ghs[lb])));
  float zg = 1.f / (1.f + __expf(-(gis[lb + 2048] + ghs[lb + 2048])));
  float nv = gis[lb + 4096] + r * ghs[lb + 4096];
  float t2 = __expf(-2.f * fabsf(nv));
  float n = (1.f - t2) / (1.f + t2);
  n = (nv >= 0.f) ? n : -n;
  size_t g = (size_t)(row0 + bl) * 2048 + j;
  ho[g] = (1.f - zg) * n + zg * hp[g];
}

// ---------------- host ----------------
extern "C" void kernel_launch(void* const* d_in, const int* in_sizes, int n_in,
                              void* d_out, int out_size, void* d_ws, size_t ws_size,
                              hipStream_t stream) {
  const float* x_t = (const float*)d_in[0];
  const float* a_prev = (const float*)d_in[1];
  const float* h_prev = (const float*)d_in[2];
  const float* eps = (const float*)d_in[3];
  const float* prior_w1 = (const float*)d_in[4];
  const float* prior_b1 = (const float*)d_in[5];
  const float* prior_w2 = (const float*)d_in[6];
  const float* prior_b2 = (const float*)d_in[7];
  const float* enc_w1 = (const float*)d_in[8];
  const float* enc_b1 = (const float*)d_in[9];
  const float* enc_w2 = (const float*)d_in[10];
  const float* enc_b2 = (const float*)d_in[11];
  const float* dec_w1 = (const float*)d_in[12];
  const float* dec_b1 = (const float*)d_in[13];
  const float* dec_w2 = (const float*)d_in[14];
  const float* dec_b2 = (const float*)d_in[15];
  const float* w_ih = (const float*)d_in[16];
  const float* w_hh = (const float*)d_in[17];
  const float* b_ih = (const float*)d_in[18];
  const float* b_hh = (const float*)d_in[19];

  float* out = (float*)d_out;
  float* out_h = out;
  float* out_nll = out + (size_t)B_SZ * H_SZ;
  float* out_kl = out_nll + B_SZ;
  float* out_z = out_kl + B_SZ;
  float* out_mu = out_z + (size_t)B_SZ * Z_SZ;
  float* out_lq = out_mu + (size_t)B_SZ * Z_SZ;

  char* ws = (char*)d_ws;
  size_t off = 0;
  auto alloc = [&](size_t bytes) {
    void* p = ws + off;
    off += (bytes + 255) & ~(size_t)255;
    return p;
  };

  const bool tier1 = ws_size >= ((size_t)160 << 20);  // need ~152.4MB

  if (tier1) {
    // ---- tier 1: full-batch MFMA pipeline, 152.3 MB ----
    uint16_t* pw1 = (uint16_t*)alloc((size_t)H_SZ * H_SZ * 2);       // dies after prior1
    uint16_t* pw2 = (uint16_t*)alloc((size_t)512 * H_SZ * 2);
    uint16_t* ew1 = (uint16_t*)alloc((size_t)H_SZ * 2560 * 2);       // dies after enc1
    uint16_t* ew2 = (uint16_t*)alloc((size_t)512 * H_SZ * 2);
    uint16_t* dw1 = (uint16_t*)alloc((size_t)H_SZ * 2304 * 2);
    uint16_t* dw2 = (uint16_t*)alloc((size_t)1024 * H_SZ * 2);
    uint16_t* wih = (uint16_t*)alloc((size_t)6144 * 832 * 2);
    uint16_t* whh = (uint16_t*)alloc((size_t)6144 * H_SZ * 2);
    uint16_t* xh = (uint16_t*)alloc((size_t)B_SZ * 2560 * 2);
    uint16_t* zh = (uint16_t*)alloc((size_t)B_SZ * 2304 * 2);
    uint16_t* rnn = (uint16_t*)alloc((size_t)B_SZ * 832 * 2);
    uint16_t* h1 = (uint16_t*)alloc((size_t)B_SZ * H_SZ * 2);
    uint16_t* pstats = (uint16_t*)alloc((size_t)B_SZ * 512 * 2);     // bf16 stats
    uint16_t* estats = (uint16_t*)alloc((size_t)B_SZ * 512 * 2);
    uint16_t* decout = (uint16_t*)alloc((size_t)B_SZ * 1024 * 2);    // bf16 dec
    // GRU slice buffers (512 rows x 6144) OVERLAY pw1 / ew1 (dead before GRU phase)
    uint16_t* ghs = pw1;  // 6.29MB <= 8.39MB
    uint16_t* gis = ew1;  // 6.29MB <= 10.49MB

    auto conv = [&](const float* src, uint16_t* dst, int R, int C, int ld) {
      int ng = R * (C / 8);
      convert_kernel<<<dim3((ng + 255) / 256), dim3(256), 0, stream>>>(src, dst, C / 8, C, ld, ng);
    };
    conv(prior_w1, pw1, H_SZ, H_SZ, H_SZ);
    conv(prior_w2, pw2, 512, H_SZ, H_SZ);
    conv(enc_w1, ew1, H_SZ, 2560, 2560);
    conv(enc_w2, ew2, 512, H_SZ, H_SZ);
    conv(dec_w1, dw1, H_SZ, 2304, 2304);
    conv(dec_w2, dw2, 1024, H_SZ, H_SZ);
    conv(w_ih, wih, 6144, 832, 832);
    conv(w_hh, whh, 6144, H_SZ, H_SZ);
    conv(x_t, xh, B_SZ, 512, 2560);
    conv(h_prev, xh + 512, B_SZ, H_SZ, 2560);
    conv(h_prev, zh + 256, B_SZ, H_SZ, 2304);
    conv(x_t, rnn, B_SZ, 512, 832);
    conv(a_prev, rnn + 768, B_SZ, 64, 832);

    auto gemm = [&](const uint16_t* A, int lda, const uint16_t* W, const float* bias,
                    void* C, int ldc, int M, int N, int K, int epi) {
      int Nt = N / 128;
      dim3 grid((M / 128) * Nt);
      if (epi == 1)
        gemm_bt<1><<<grid, dim3(256), 0, stream>>>(A, lda, W, bias, C, ldc, Nt, K);
      else
        gemm_bt<2><<<grid, dim3(256), 0, stream>>>(A, lda, W, bias, C, ldc, Nt, K);
    };

    gemm(xh + 512, 2560, pw1, prior_b1, h1, H_SZ, B_SZ, H_SZ, H_SZ, 1);
    gemm(h1, H_SZ, pw2, prior_b2, pstats, 512, B_SZ, 512, H_SZ, 2);
    gemm(xh, 2560, ew1, enc_b1, h1, H_SZ, B_SZ, H_SZ, 2560, 1);
    gemm(h1, H_SZ, ew2, enc_b2, estats, 512, B_SZ, 512, H_SZ, 2);
    z_kernel_t1<<<dim3(B_SZ * Z_SZ / 256), dim3(256), 0, stream>>>(
        estats, eps, out_z, out_mu, out_lq, zh, rnn);
    gemm(zh, 2304, dw1, dec_b1, h1, H_SZ, B_SZ, H_SZ, 2304, 1);
    gemm(h1, H_SZ, dw2, dec_b2, decout, 1024, B_SZ, 1024, H_SZ, 2);
    // GRU in 8 slices of 512 rows; ghs/gis reuse dead pw1/ew1 space
    for (int s = 0; s < 8; ++s) {
      int r0 = s * 512;
      gemm(xh + (size_t)r0 * 2560 + 512, 2560, whh, b_hh, ghs, 6144, 512, 6144, H_SZ, 2);
      gemm(rnn + (size_t)r0 * 832, 832, wih, b_ih, gis, 6144, 512, 6144, 832, 2);
      gru_fused_t1<<<dim3(512), dim3(256), 0, stream>>>(
          gis, ghs, h_prev, x_t, decout, pstats, estats, out_h, out_nll, out_kl, r0);
    }
  } else {
    // ---- tier 2: naive fp32 sliced (fits tiny ws) ----
    int R = 512;
    while (R > 32 && (size_t)R * 66560 + 4096 > ws_size) R >>= 1;
    float* h1s = (float*)alloc((size_t)R * 2048 * 4);
    float* psts = (float*)alloc((size_t)R * 512 * 4);
    float* ests = (float*)alloc((size_t)R * 512 * 4);
    float* decs = (float*)alloc((size_t)R * 1024 * 4);
    float* zs = (float*)alloc((size_t)R * 256 * 4);
    float* gis = (float*)alloc((size_t)R * 6144 * 4);
    float* ghs = (float*)alloc((size_t)R * 6144 * 4);
    const float* dummy = x_t;

    auto nv = [&](const float* A0, int ld0, int s1, const float* A1, int ld1, int s2,
                  const float* A2, int ld2, const float* W, const float* bias,
                  float* C, int M, int N, int K, int relu) {
      dim3 grid(M * (N / 256));
      if (relu)
        gemm_nv<1><<<grid, dim3(256), 0, stream>>>(A0, ld0, s1, A1, ld1, s2, A2, ld2, W, bias, C, N, K);
      else
        gemm_nv<0><<<grid, dim3(256), 0, stream>>>(A0, ld0, s1, A1, ld1, s2, A2, ld2, W, bias, C, N, K);
    };

    for (int s = 0; s < B_SZ / R; ++s) {
      int r0 = s * R;
      const float* xs = x_t + (size_t)r0 * 512;
      const float* hs = h_prev + (size_t)r0 * 2048;
      const float* as = a_prev + (size_t)r0 * 64;
      // prior
      nv(hs, 2048, 2048, dummy, 0, 2048, dummy, 0, prior_w1, prior_b1, h1s, R, 2048, 2048, 1);
      nv(h1s, 2048, 2048, dummy, 0, 2048, dummy, 0, prior_w2, prior_b2, psts, R, 512, 2048, 0);
      // encoder  [x|h]
      nv(xs, 512, 512, hs, 2048, 2560, dummy, 0, enc_w1, enc_b1, h1s, R, 2048, 2560, 1);
      nv(h1s, 2048, 2048, dummy, 0, 2048, dummy, 0, enc_w2, enc_b2, ests, R, 512, 2048, 0);
      // z
      z_nv<<<dim3((R * 256 + 255) / 256), dim3(256), 0, stream>>>(
          ests, eps, out_z, out_mu, out_lq, zs, r0, R);
      // decoder  [z|h]
      nv(zs, 256, 256, hs, 2048, 2304, dummy, 0, dec_w1, dec_b1, h1s, R, 2048, 2304, 1);
      nv(h1s, 2048, 2048, dummy, 0, 2048, dummy, 0, dec_w2, dec_b2, decs, R, 1024, 2048, 0);
      // GRU gates  gh: h ; gi: [x|z|a]
      nv(hs, 2048, 2048, dummy, 0, 2048, dummy, 0, w_hh, b_hh, ghs, R, 6144, 2048, 0);
      nv(xs, 512, 512, zs, 256, 768, as, 64, w_ih, b_ih, gis, R, 6144, 832, 0);
      // epilogues
      nll_nv<<<dim3(R), dim3(64), 0, stream>>>(x_t, decs, out_nll, r0);
      kl_nv<<<dim3(R), dim3(64), 0, stream>>>(psts, ests, out_kl, r0);
      gru_nv<<<dim3((R * 2048 + 255) / 256), dim3(256), 0, stream>>>(
          gis, ghs, h_prev, out_h, r0, R);
    }
  }
}

// Round 16
// 567.859 us; speedup vs baseline: 1.7312x; 1.7312x over previous
//
#include <hip/hip_runtime.h>
#include <stdint.h>

// R15 lesson: never bail silently on ws_size; fit it. ws_size ≈ 256 MiB (old
// 269.75MB demand failed; 152MB passed). This layout: 179.57 MB + tier-2 fallback.

#define B_SZ 4096
#define H_SZ 2048
#define Z_SZ 256

typedef __attribute__((ext_vector_type(4))) float f32x4;
typedef __attribute__((ext_vector_type(8))) short s16x8;

__device__ __forceinline__ uint16_t f2b(float f) {
  union { float f; uint32_t u; } v; v.f = f;
  uint32_t u = v.u;
  uint32_t r = (u + 0x7FFFu + ((u >> 16) & 1u)) >> 16;
  return (uint16_t)r;
}
__device__ __forceinline__ float b2f(uint16_t h) {
  union { uint32_t u; float f; } v; v.u = ((uint32_t)h) << 16; return v.f;
}
__device__ __forceinline__ float clip10(float v) { return fminf(fmaxf(v, -10.0f), 10.0f); }

// ---------------- fp32 [R,C] -> bf16 strided [R, dstLd] ----------------
__global__ void convert_kernel(const float* __restrict__ src, uint16_t* __restrict__ dst,
                               int C8, int C, int dstLd, int ngroups) {
  int i = blockIdx.x * 256 + threadIdx.x;
  if (i >= ngroups) return;
  int row = i / C8;
  int cg = i - row * C8;
  const f32x4* s = (const f32x4*)(src + (size_t)row * C + (size_t)cg * 8);
  f32x4 lo = s[0], hi = s[1];
  s16x8 p;
  p[0] = (short)f2b(lo[0]); p[1] = (short)f2b(lo[1]);
  p[2] = (short)f2b(lo[2]); p[3] = (short)f2b(lo[3]);
  p[4] = (short)f2b(hi[0]); p[5] = (short)f2b(hi[1]);
  p[6] = (short)f2b(hi[2]); p[7] = (short)f2b(hi[3]);
  *(s16x8*)(dst + (size_t)row * dstLd + (size_t)cg * 8) = p;
}

// ---------------- async global->LDS, 16B per lane ----------------
__device__ __forceinline__ void gload_lds16(const uint16_t* g, uint16_t* l) {
  __builtin_amdgcn_global_load_lds(
      (const __attribute__((address_space(1))) uint32_t*)g,
      (__attribute__((address_space(3))) uint32_t*)(uintptr_t)(void*)l,
      16, 0, 0);
}

// ---- MFMA bf16 GEMM, split-A (up to 3 concat K-regions), optional split-N output.
// EPI: 1 = relu bf16 -> C0 ; 2 = bf16 -> C0 ; 3 = cols<splitN relu->C0, else ->C1
template <int EPI>
__global__ __launch_bounds__(256)
void gemm_bt(const uint16_t* __restrict__ A0, int lda0, int ks1,
             const uint16_t* __restrict__ A1, int lda1, int ks2,
             const uint16_t* __restrict__ A2, int lda2,
             const uint16_t* __restrict__ W,
             const float* __restrict__ bias0, const float* __restrict__ bias1,
             uint16_t* __restrict__ C0, int ldc0, int splitN,
             uint16_t* __restrict__ C1, int ldc1,
             int Nt, int K) {
  __shared__ uint16_t As[128 * 64];
  __shared__ uint16_t Ws[128 * 64];
  int mtile = blockIdx.x / Nt;
  int ntile = blockIdx.x - mtile * Nt;
  const int row0 = mtile << 7, col0 = ntile << 7;
  const int t = threadIdx.x;
  const int w = t >> 6, l = t & 63;
  const int wr = w >> 1, wc = w & 1;
  const int sr = l >> 3, scg = l & 7;
  const int fr = l & 15, fq = l >> 4;

  f32x4 acc[4][4] = {};

  const uint16_t* Wbase = W + (size_t)(col0 + w * 32 + sr) * K + scg * 8;

  for (int k0 = 0; k0 < K; k0 += 64) {
    const uint16_t* ab; int ald, koff;   // wave-uniform region select
    if (k0 < ks1)      { ab = A0; ald = lda0; koff = k0; }
    else if (k0 < ks2) { ab = A1; ald = lda1; koff = k0 - ks1; }
    else               { ab = A2; ald = lda2; koff = k0 - ks2; }
    const uint16_t* Abase = ab + (size_t)(row0 + w * 32 + sr) * ald + koff + scg * 8;
#pragma unroll
    for (int j = 0; j < 4; ++j)
      gload_lds16(Abase + (size_t)(j * 8) * ald, &As[(w * 32 + j * 8) * 64]);
#pragma unroll
    for (int j = 0; j < 4; ++j)
      gload_lds16(Wbase + (size_t)(j * 8) * K + k0, &Ws[(w * 32 + j * 8) * 64]);
    __syncthreads();
#pragma unroll
    for (int ks = 0; ks < 2; ++ks) {
      s16x8 fa[4], fb[4];
#pragma unroll
      for (int m = 0; m < 4; ++m)
        fa[m] = *(const s16x8*)&As[(wr * 64 + m * 16 + fr) * 64 + ks * 32 + fq * 8];
#pragma unroll
      for (int n = 0; n < 4; ++n)
        fb[n] = *(const s16x8*)&Ws[(wc * 64 + n * 16 + fr) * 64 + ks * 32 + fq * 8];
#pragma unroll
      for (int m = 0; m < 4; ++m)
#pragma unroll
        for (int n = 0; n < 4; ++n)
          acc[m][n] = __builtin_amdgcn_mfma_f32_16x16x32_bf16(fa[m], fb[n], acc[m][n], 0, 0, 0);
    }
    __syncthreads();
  }

#pragma unroll
  for (int m = 0; m < 4; ++m) {
    int grow = row0 + wr * 64 + m * 16 + fq * 4;
#pragma unroll
    for (int n = 0; n < 4; ++n) {
      int gcol = col0 + wc * 64 + n * 16 + fr;
      bool first = (EPI != 3) || (gcol < splitN);
      float bs = first ? bias0[gcol] : bias1[gcol - splitN];
#pragma unroll
      for (int i = 0; i < 4; ++i) {
        float v = acc[m][n][i] + bs;
        if (EPI == 1 || (EPI == 3 && first)) v = fmaxf(v, 0.0f);
        if (first)
          C0[(size_t)(grow + i) * ldc0 + gcol] = f2b(v);
        else
          C1[(size_t)(grow + i) * ldc1 + (gcol - splitN)] = f2b(v);
      }
    }
  }
}

// ---------------- reparameterization: bf16 stats -> z outputs + zbuf ----------------
__global__ void z_kernel_t1(const uint16_t* __restrict__ es, const float* __restrict__ eps,
                            float* __restrict__ oz, float* __restrict__ omu,
                            float* __restrict__ olq, uint16_t* __restrict__ zbuf) {
  int i = blockIdx.x * 256 + threadIdx.x;  // B*Z
  int b = i >> 8, j = i & 255;
  float mu = b2f(es[(size_t)b * 512 + j]);
  float lq = clip10(b2f(es[(size_t)b * 512 + 256 + j]));
  float z = mu + eps[i] * __expf(0.5f * lq);
  oz[i] = z; omu[i] = mu; olq[i] = lq;
  zbuf[i] = f2b(z);
}

__device__ __forceinline__ float block_sum256(float v) {
  __shared__ float ps[4];
#pragma unroll
  for (int o = 32; o > 0; o >>= 1) v += __shfl_xor(v, o, 64);
  int l = threadIdx.x & 63, w = threadIdx.x >> 6;
  if (l == 0) ps[w] = v;
  __syncthreads();
  float r = ps[0] + ps[1] + ps[2] + ps[3];
  __syncthreads();
  return r;
}

// ---------------- epilogue: GRU + nll + kl (full batch, bf16 operands) ----------
__global__ __launch_bounds__(256)
void gru_fused_t1(const uint16_t* __restrict__ gi, const uint16_t* __restrict__ gh,
                  const float* __restrict__ hp, const float* __restrict__ x,
                  const uint16_t* __restrict__ dec, const uint16_t* __restrict__ pst,
                  const uint16_t* __restrict__ es,
                  float* __restrict__ out_h, float* __restrict__ out_nll,
                  float* __restrict__ out_kl) {
  int b = blockIdx.x, t = threadIdx.x;
  size_t gbase = (size_t)b * 6144 + (size_t)t * 8;
  s16x8 ir = *(const s16x8*)(gi + gbase);
  s16x8 iz = *(const s16x8*)(gi + gbase + 2048);
  s16x8 inn = *(const s16x8*)(gi + gbase + 4096);
  s16x8 hr = *(const s16x8*)(gh + gbase);
  s16x8 hz = *(const s16x8*)(gh + gbase + 2048);
  s16x8 hn = *(const s16x8*)(gh + gbase + 4096);
  size_t hbase = (size_t)b * 2048 + (size_t)t * 8;
  f32x4 h0 = *(const f32x4*)(hp + hbase);
  f32x4 h1v = *(const f32x4*)(hp + hbase + 4);
  f32x4 o0, o1;
#pragma unroll
  for (int e = 0; e < 8; ++e) {
    float r = 1.f / (1.f + __expf(-(b2f((uint16_t)ir[e]) + b2f((uint16_t)hr[e]))));
    float zg = 1.f / (1.f + __expf(-(b2f((uint16_t)iz[e]) + b2f((uint16_t)hz[e]))));
    float nv = b2f((uint16_t)inn[e]) + r * b2f((uint16_t)hn[e]);
    float t2 = __expf(-2.f * fabsf(nv));
    float n = (1.f - t2) / (1.f + t2);
    n = (nv >= 0.f) ? n : -n;
    float hv = (e < 4) ? h0[e] : h1v[e - 4];
    float o = (1.f - zg) * n + zg * hv;
    if (e < 4) o0[e] = o; else o1[e - 4] = o;
  }
  *(f32x4*)(out_h + hbase) = o0;
  *(f32x4*)(out_h + hbase + 4) = o1;

  float s = 0.f;
#pragma unroll
  for (int rr = 0; rr < 2; ++rr) {
    int j = t + rr * 256;
    float mu = b2f(dec[(size_t)b * 1024 + j]);
    float lx = clip10(b2f(dec[(size_t)b * 1024 + 512 + j]));
    float d = x[(size_t)b * 512 + j] - mu;
    s += d * d * __expf(-lx) + lx;
  }
  s = block_sum256(s);
  if (t == 0) out_nll[b] = 0.5f * s;

  float mu_p = b2f(pst[(size_t)b * 512 + t]);
  float lp = b2f(pst[(size_t)b * 512 + 256 + t]);
  float mu_q = b2f(es[(size_t)b * 512 + t]);
  float lq = clip10(b2f(es[(size_t)b * 512 + 256 + t]));
  float dq = mu_q - mu_p;
  float enl = __expf(-lp);
  float kv = dq * dq * enl + __expf(lq) * enl + (lp - lq) - 1.0f;
  kv = block_sum256(kv);
  if (t == 0) out_kl[b] = 0.5f * kv;
}

// ================= tier 2 fallback: naive fp32 sliced pipeline =================
template <int MODE>
__global__ __launch_bounds__(256)
void gemm_nv(const float* __restrict__ A0, int ld0, int s1,
             const float* __restrict__ A1, int ld1, int s2,
             const float* __restrict__ A2, int ld2,
             const float* __restrict__ W, const float* __restrict__ bias,
             float* __restrict__ C, int N, int K) {
  int nb = N >> 8;
  int m = blockIdx.x / nb;
  int n = (blockIdx.x - m * nb) * 256 + threadIdx.x;
  const float* w = W + (size_t)n * K;
  float acc = 0.f;
  int k = 0;
  for (; k < s1; ++k) acc += A0[(size_t)m * ld0 + k] * w[k];
  for (; k < s2; ++k) acc += A1[(size_t)m * ld1 + (k - s1)] * w[k];
  for (; k < K; ++k) acc += A2[(size_t)m * ld2 + (k - s2)] * w[k];
  acc += bias[n];
  if (MODE == 1) acc = fmaxf(acc, 0.f);
  C[(size_t)m * N + n] = acc;
}

__global__ void z_nv(const float* __restrict__ ests, const float* __restrict__ eps,
                     float* __restrict__ oz, float* __restrict__ omu,
                     float* __restrict__ olq, float* __restrict__ zs, int row0, int nR) {
  int i = blockIdx.x * 256 + threadIdx.x;
  if (i >= nR * 256) return;
  int bl = i >> 8, j = i & 255;
  size_t g = (size_t)(row0 + bl) * 256 + j;
  float mu = ests[(size_t)bl * 512 + j];
  float lq = clip10(ests[(size_t)bl * 512 + 256 + j]);
  float z = mu + eps[g] * __expf(0.5f * lq);
  oz[g] = z; omu[g] = mu; olq[g] = lq;
  zs[(size_t)bl * 256 + j] = z;
}

__global__ void nll_nv(const float* __restrict__ x, const float* __restrict__ decs,
                       float* __restrict__ out, int row0) {
  int bl = blockIdx.x, l = threadIdx.x;
  int gb = row0 + bl;
  float s = 0.f;
  for (int j = l; j < 512; j += 64) {
    float mu = decs[(size_t)bl * 1024 + j];
    float lx = clip10(decs[(size_t)bl * 1024 + 512 + j]);
    float d = x[(size_t)gb * 512 + j] - mu;
    s += d * d * __expf(-lx) + lx;
  }
#pragma unroll
  for (int o = 32; o > 0; o >>= 1) s += __shfl_xor(s, o, 64);
  if (l == 0) out[gb] = 0.5f * s;
}

__global__ void kl_nv(const float* __restrict__ psts, const float* __restrict__ ests,
                      float* __restrict__ out, int row0) {
  int bl = blockIdx.x, l = threadIdx.x;
  int gb = row0 + bl;
  float s = 0.f;
  for (int j = l; j < 256; j += 64) {
    float mu_p = psts[(size_t)bl * 512 + j];
    float lp = psts[(size_t)bl * 512 + 256 + j];
    float mu_q = ests[(size_t)bl * 512 + j];
    float lq = clip10(ests[(size_t)bl * 512 + 256 + j]);
    float d = mu_q - mu_p;
    float enl = __expf(-lp);
    s += d * d * enl + __expf(lq) * enl + (lp - lq) - 1.0f;
  }
#pragma unroll
  for (int o = 32; o > 0; o >>= 1) s += __shfl_xor(s, o, 64);
  if (l == 0) out[gb] = 0.5f * s;
}

__global__ void gru_nv(const float* __restrict__ gis, const float* __restrict__ ghs,
                       const float* __restrict__ hp, float* __restrict__ ho,
                       int row0, int nR) {
  int i = blockIdx.x * 256 + threadIdx.x;
  if (i >= nR * 2048) return;
  int bl = i >> 11, j = i & 2047;
  size_t lb = (size_t)bl * 6144 + j;
  float r = 1.f / (1.f + __expf(-(gis[lb] + ghs[lb])));
  float zg = 1.f / (1.f + __expf(-(gis[lb + 2048] + ghs[lb + 2048])));
  float nv = gis[lb + 4096] + r * ghs[lb + 4096];
  float t2 = __expf(-2.f * fabsf(nv));
  float n = (1.f - t2) / (1.f + t2);
  n = (nv >= 0.f) ? n : -n;
  size_t g = (size_t)(row0 + bl) * 2048 + j;
  ho[g] = (1.f - zg) * n + zg * hp[g];
}

// ---------------- host ----------------
extern "C" void kernel_launch(void* const* d_in, const int* in_sizes, int n_in,
                              void* d_out, int out_size, void* d_ws, size_t ws_size,
                              hipStream_t stream) {
  const float* x_t = (const float*)d_in[0];
  const float* a_prev = (const float*)d_in[1];
  const float* h_prev = (const float*)d_in[2];
  const float* eps = (const float*)d_in[3];
  const float* prior_w1 = (const float*)d_in[4];
  const float* prior_b1 = (const float*)d_in[5];
  const float* prior_w2 = (const float*)d_in[6];
  const float* prior_b2 = (const float*)d_in[7];
  const float* enc_w1 = (const float*)d_in[8];
  const float* enc_b1 = (const float*)d_in[9];
  const float* enc_w2 = (const float*)d_in[10];
  const float* enc_b2 = (const float*)d_in[11];
  const float* dec_w1 = (const float*)d_in[12];
  const float* dec_b1 = (const float*)d_in[13];
  const float* dec_w2 = (const float*)d_in[14];
  const float* dec_b2 = (const float*)d_in[15];
  const float* w_ih = (const float*)d_in[16];
  const float* w_hh = (const float*)d_in[17];
  const float* b_ih = (const float*)d_in[18];
  const float* b_hh = (const float*)d_in[19];

  float* out = (float*)d_out;
  float* out_h = out;
  float* out_nll = out + (size_t)B_SZ * H_SZ;
  float* out_kl = out_nll + B_SZ;
  float* out_z = out_kl + B_SZ;
  float* out_mu = out_z + (size_t)B_SZ * Z_SZ;
  float* out_lq = out_mu + (size_t)B_SZ * Z_SZ;

  char* ws = (char*)d_ws;
  size_t off = 0;
  auto alloc = [&](size_t bytes) {
    void* p = ws + off;
    off += (bytes + 255) & ~(size_t)255;
    return p;
  };

  const size_t T1_DEMAND = 179568640;  // exact byte sum of tier-1 layout below
  if (ws_size >= T1_DEMAND) {
    // ---- tier 1: fused/full-batch MFMA pipeline ----
    uint16_t* wcat = (uint16_t*)alloc((size_t)8192 * 2048 * 2);  // [pw1;whh] dead after GEMM A
    uint16_t* pw2 = (uint16_t*)alloc((size_t)512 * 2048 * 2);    // dead after prior2
    uint16_t* ew1 = (uint16_t*)alloc((size_t)2048 * 2560 * 2);   // dead after enc1
    uint16_t* ew2 = (uint16_t*)alloc((size_t)512 * 2048 * 2);    // dead after enc2
    uint16_t* dw1 = (uint16_t*)alloc((size_t)2048 * 2304 * 2);   // dead after dec1
    uint16_t* dw2 = (uint16_t*)alloc((size_t)1024 * 2048 * 2);
    uint16_t* wih = (uint16_t*)alloc((size_t)6144 * 832 * 2);
    uint16_t* xh = (uint16_t*)alloc((size_t)B_SZ * 2560 * 2);    // [x|h] bf16
    uint16_t* zbuf = (uint16_t*)alloc((size_t)B_SZ * 256 * 2);
    uint16_t* abuf = (uint16_t*)alloc((size_t)B_SZ * 64 * 2);
    uint16_t* h1 = (uint16_t*)alloc((size_t)B_SZ * 2048 * 2);
    uint16_t* pstats = (uint16_t*)alloc((size_t)B_SZ * 512 * 2);
    uint16_t* estats = (uint16_t*)alloc((size_t)B_SZ * 512 * 2);
    uint16_t* decout = (uint16_t*)alloc((size_t)B_SZ * 1024 * 2);
    uint16_t* gh = (uint16_t*)alloc((size_t)B_SZ * 6144 * 2);
    // gi (50.33MB) overlays wcat..dw1 (57.67MB), all dead before the gi GEMM
    uint16_t* gi = wcat;

    auto conv = [&](const float* src, uint16_t* dst, int R, int C, int ld) {
      int ng = R * (C / 8);
      convert_kernel<<<dim3((ng + 255) / 256), dim3(256), 0, stream>>>(src, dst, C / 8, C, ld, ng);
    };
    conv(prior_w1, wcat, 2048, 2048, 2048);                    // wcat rows 0-2047
    conv(w_hh, wcat + (size_t)2048 * 2048, 6144, 2048, 2048);  // wcat rows 2048-8191
    conv(prior_w2, pw2, 512, 2048, 2048);
    conv(enc_w1, ew1, 2048, 2560, 2560);
    conv(enc_w2, ew2, 512, 2048, 2048);
    conv(dec_w1, dw1, 2048, 2304, 2304);
    conv(dec_w2, dw2, 1024, 2048, 2048);
    conv(w_ih, wih, 6144, 832, 832);
    conv(x_t, xh, B_SZ, 512, 2560);
    conv(h_prev, xh + 512, B_SZ, 2048, 2560);
    conv(a_prev, abuf, B_SZ, 64, 64);

    // single-A convenience wrapper
    auto gemm1 = [&](const uint16_t* A, int lda, const uint16_t* W, const float* bias,
                     uint16_t* C, int ldc, int N, int K, int relu) {
      int Nt = N / 128;
      dim3 grid((B_SZ / 128) * Nt);
      if (relu)
        gemm_bt<1><<<grid, dim3(256), 0, stream>>>(A, lda, K, A, lda, K, A, lda, W,
                                                   bias, bias, C, ldc, N, C, ldc, Nt, K);
      else
        gemm_bt<2><<<grid, dim3(256), 0, stream>>>(A, lda, K, A, lda, K, A, lda, W,
                                                   bias, bias, C, ldc, N, C, ldc, Nt, K);
    };

    // GEMM A (fused prior1 + gh): A = h bf16, W = wcat, N=8192, K=2048, 2048 blocks
    gemm_bt<3><<<dim3((B_SZ / 128) * 64), dim3(256), 0, stream>>>(
        xh + 512, 2560, 2048, xh, 2560, 2048, xh, 2560, wcat,
        prior_b1, b_hh, h1, 2048, 2048, gh, 6144, 64, 2048);
    // prior2: h1 -> pstats
    gemm1(h1, 2048, pw2, prior_b2, pstats, 512, 512, 2048, 0);
    // enc1: [x|h] -> h1 (relu)
    gemm1(xh, 2560, ew1, enc_b1, h1, 2048, 2048, 2560, 1);
    // enc2: h1 -> estats
    gemm1(h1, 2048, ew2, enc_b2, estats, 512, 512, 2048, 0);
    // reparameterize
    z_kernel_t1<<<dim3(B_SZ * Z_SZ / 256), dim3(256), 0, stream>>>(
        estats, eps, out_z, out_mu, out_lq, zbuf);
    // dec1: A = [z|h] split regions (zbuf lda 256 for k<256, xh+512 lda 2560 after)
    gemm_bt<1><<<dim3((B_SZ / 128) * 16), dim3(256), 0, stream>>>(
        zbuf, 256, 256, xh + 512, 2560, 2304, xh, 2560, dw1,
        dec_b1, dec_b1, h1, 2048, 2048, h1, 2048, 16, 2304);
    // dec2: h1 -> decout
    gemm1(h1, 2048, dw2, dec_b2, decout, 1024, 1024, 2048, 0);
    // gi: A = [x|z|a] split regions, full batch, N=6144, K=832, 1536 blocks
    gemm_bt<2><<<dim3((B_SZ / 128) * 48), dim3(256), 0, stream>>>(
        xh, 2560, 512, zbuf, 256, 768, abuf, 64, wih,
        b_ih, b_ih, gi, 6144, 6144, gi, 6144, 48, 832);
    // epilogue: GRU + nll + kl, full batch
    gru_fused_t1<<<dim3(B_SZ), dim3(256), 0, stream>>>(
        gi, gh, h_prev, x_t, decout, pstats, estats, out_h, out_nll, out_kl);
  } else {
    // ---- tier 2: naive fp32 sliced (fits tiny ws; correctness guarantee) ----
    int R = 512;
    while (R > 32 && (size_t)R * 66560 + 4096 > ws_size) R >>= 1;
    float* h1s = (float*)alloc((size_t)R * 2048 * 4);
    float* psts = (float*)alloc((size_t)R * 512 * 4);
    float* ests = (float*)alloc((size_t)R * 512 * 4);
    float* decs = (float*)alloc((size_t)R * 1024 * 4);
    float* zs = (float*)alloc((size_t)R * 256 * 4);
    float* gis = (float*)alloc((size_t)R * 6144 * 4);
    float* ghs = (float*)alloc((size_t)R * 6144 * 4);
    const float* dummy = x_t;

    auto nv = [&](const float* A0, int ld0, int s1, const float* A1, int ld1, int s2,
                  const float* A2, int ld2, const float* W, const float* bias,
                  float* C, int M, int N, int K, int relu) {
      dim3 grid(M * (N / 256));
      if (relu)
        gemm_nv<1><<<grid, dim3(256), 0, stream>>>(A0, ld0, s1, A1, ld1, s2, A2, ld2, W, bias, C, N, K);
      else
        gemm_nv<0><<<grid, dim3(256), 0, stream>>>(A0, ld0, s1, A1, ld1, s2, A2, ld2, W, bias, C, N, K);
    };

    for (int s = 0; s < B_SZ / R; ++s) {
      int r0 = s * R;
      const float* xs = x_t + (size_t)r0 * 512;
      const float* hs = h_prev + (size_t)r0 * 2048;
      const float* as = a_prev + (size_t)r0 * 64;
      nv(hs, 2048, 2048, dummy, 0, 2048, dummy, 0, prior_w1, prior_b1, h1s, R, 2048, 2048, 1);
      nv(h1s, 2048, 2048, dummy, 0, 2048, dummy, 0, prior_w2, prior_b2, psts, R, 512, 2048, 0);
      nv(xs, 512, 512, hs, 2048, 2560, dummy, 0, enc_w1, enc_b1, h1s, R, 2048, 2560, 1);
      nv(h1s, 2048, 2048, dummy, 0, 2048, dummy, 0, enc_w2, enc_b2, ests, R, 512, 2048, 0);
      z_nv<<<dim3((R * 256 + 255) / 256), dim3(256), 0, stream>>>(
          ests, eps, out_z, out_mu, out_lq, zs, r0, R);
      nv(zs, 256, 256, hs, 2048, 2304, dummy, 0, dec_w1, dec_b1, h1s, R, 2048, 2304, 1);
      nv(h1s, 2048, 2048, dummy, 0, 2048, dummy, 0, dec_w2, dec_b2, decs, R, 1024, 2048, 0);
      nv(hs, 2048, 2048, dummy, 0, 2048, dummy, 0, w_hh, b_hh, ghs, R, 6144, 2048, 0);
      nv(xs, 512, 512, zs, 256, 768, as, 64, w_ih, b_ih, gis, R, 6144, 832, 0);
      nll_nv<<<dim3(R), dim3(64), 0, stream>>>(x_t, decs, out_nll, r0);
      kl_nv<<<dim3(R), dim3(64), 0, stream>>>(psts, ests, out_kl, r0);
      gru_nv<<<dim3((R * 2048 + 255) / 256), dim3(256), 0, stream>>>(
          gis, ghs, h_prev, out_h, r0, R);
    }
  }
}